// Round 10
// baseline (123.308 us; speedup 1.0000x reference)
//
#include <hip/hip_runtime.h>
#include <hip/hip_bf16.h>
#include <math.h>

// MultiHeadAttentionQuantum, B=2048 S=1 E=1024 H=128 DK=NW=8
// All inputs/outputs float32.
//
// Algebra: S==1 -> attention out == v = x @ Wv^T (wq,wk dead).
// RX compose additively; CNOTs are XOR basis permutations ->
//   t_j = cos(v_j + rx_j);  qout[0]=t1*...*t7;  qout[w>=1]=t0*...*tw
// out = qout @ Wc^T + bc
//
// R9 post-mortem: BK=128/64KB LDS regressed (m132 lesson). R8 best (112.3us):
// BK=64, 32KB LDS, 512thr/8 waves, frag-ordered async staging, quantum fused
// into GEMM1 epilogue. R10 = R8 minus the cvt kernel: GEMM1 stages x/wv with
// in-staging f32->bf16 cvt (R4-proven) + side-converts wc; GEMM2 unchanged.

#define BB 2048
#define EN 1024

typedef short s16x8 __attribute__((ext_vector_type(8)));
typedef float f32x4 __attribute__((ext_vector_type(4)));

union Frag { s16x8 v; __hip_bfloat16 h[8]; };

__device__ inline s16x8 cvt_frag(f32x4 lo, f32x4 hi) {
    Frag u;
    #pragma unroll
    for (int j = 0; j < 4; ++j) {
        u.h[j]     = __float2bfloat16(lo[j]);
        u.h[4 + j] = __float2bfloat16(hi[j]);
    }
    return u.v;
}

// async 16B/lane global -> LDS (lds base wave-uniform; HW adds lane*16)
__device__ inline void gll16(const __hip_bfloat16* g, __hip_bfloat16* l) {
    __builtin_amdgcn_global_load_lds(
        (const __attribute__((address_space(1))) void*)g,
        (__attribute__((address_space(3))) void*)l,
        16, 0, 0);
}

// Kernel 1: V = quantum(x @ Wv^T) (bf16), + side-convert wc -> wcb.
// Tile 64x64, BK=64 (16 iters), 512 thr = 8 waves (4m x 2n), wave tile 16x32.
// LDS 32 KB: 2 buffers x 8192 elems; frag-ordered (A tile (mt,kt) at
// (mt*2+kt)*512, B tile (nt,kt) at 4096+(nt*2+kt)*512; lane frag +lane*8).
// Staging: f32 global -> VGPR -> cvt -> LDS (2 frag-tiles per thread... 1 each
// of 16 tiles per wave pair: 512 thr cover 16 tiles x 512 elems / 8 = exactly
// 1 frag (8 elems) per thread per tile-pair -> each thread stages 2 frags).
__global__ __launch_bounds__(512, 4) void gemm1q_kernel(
        const float* __restrict__ x, const float* __restrict__ wv,
        const float* __restrict__ wc, const float* __restrict__ rx,
        __hip_bfloat16* __restrict__ wcb, __hip_bfloat16* __restrict__ V)
{
    __shared__ __align__(16) __hip_bfloat16 lds[16384];   // 32 KB

    const int tid  = threadIdx.x;
    const int wave = tid >> 6, lane = tid & 63;
    const int l15 = lane & 15, lq = lane >> 4;
    const int m0 = blockIdx.x * 64, n0 = blockIdx.y * 64;
    const int wmt = wave >> 1;          // 0..3
    const int wnt = wave & 1;           // 0..1
    const int bid = blockIdx.x + 32 * blockIdx.y;   // 0..511

    // side job: convert this block's 2048-elem chunk of wc -> wcb
    if (tid < 256) {
        const size_t off = (size_t)bid * 2048 + tid * 8;
        f32x4 lo = *(const f32x4*)(wc + off);
        f32x4 hi = *(const f32x4*)(wc + off + 4);
        *(s16x8*)(wcb + off) = cvt_frag(lo, hi);
    }

    // staging map: thread stages 2 of 16 frag-tiles: t = wave*2 + i
    const float* gsrc[2];
    int ldst[2];
    #pragma unroll
    for (int i = 0; i < 2; ++i) {
        const int t = wave * 2 + i;
        const float* base;
        int row, lofs;
        if (t < 8) { base = x;  row = m0 + (t >> 1) * 16 + l15; lofs = t * 512; }
        else       { const int u = t - 8; base = wv; row = n0 + (u >> 1) * 16 + l15; lofs = 4096 + u * 512; }
        gsrc[i] = base + (size_t)row * EN + (t & 1) * 32 + lq * 8;
        ldst[i] = lofs + lane * 8;
    }

    f32x4 acc[2] = {};
    f32x4 lo[2], hi[2];

    #pragma unroll
    for (int i = 0; i < 2; ++i) { lo[i] = *(const f32x4*)gsrc[i]; hi[i] = *(const f32x4*)(gsrc[i] + 4); }
    #pragma unroll
    for (int i = 0; i < 2; ++i) *(s16x8*)&lds[ldst[i]] = cvt_frag(lo[i], hi[i]);
    __syncthreads();

    int p = 0;
    for (int it = 1; it <= 16; ++it) {
        if (it < 16) {
            #pragma unroll
            for (int i = 0; i < 2; ++i) {
                lo[i] = *(const f32x4*)(gsrc[i] + it * 64);
                hi[i] = *(const f32x4*)(gsrc[i] + it * 64 + 4);
            }
        }
        const __hip_bfloat16* Ab = &lds[p * 8192];
        const __hip_bfloat16* Bb = Ab + 4096;
        #pragma unroll
        for (int kt = 0; kt < 2; ++kt) {
            s16x8 a = *(const s16x8*)&Ab[(wmt * 2 + kt) * 512 + lane * 8];
            #pragma unroll
            for (int j = 0; j < 2; ++j) {
                s16x8 b = *(const s16x8*)&Bb[((wnt * 2 + j) * 2 + kt) * 512 + lane * 8];
                acc[j] = __builtin_amdgcn_mfma_f32_16x16x32_bf16(a, b, acc[j], 0, 0, 0);
            }
        }
        if (it < 16) {
            const int q = p ^ 1;
            #pragma unroll
            for (int i = 0; i < 2; ++i) *(s16x8*)&lds[q * 8192 + ldst[i]] = cvt_frag(lo[i], hi[i]);
        }
        __syncthreads();
        p ^= 1;
    }

    // quantum epilogue: acc -> LDS f32 64x68 -> cos/products -> bf16 V
    float* sb = (float*)lds;                      // 17408 B, K-loop done
    #pragma unroll
    for (int j = 0; j < 2; ++j) {
        const int col = wnt * 32 + j * 16 + l15;
        #pragma unroll
        for (int r = 0; r < 4; ++r)
            sb[(wmt * 16 + lq * 4 + r) * 68 + col] = acc[j][r];
    }
    __syncthreads();
    const int row = tid >> 3, g = tid & 7;        // 64 rows x 8 groups
    const float* pv = &sb[row * 68 + g * 8];
    float t[8];
    #pragma unroll
    for (int j = 0; j < 8; ++j) t[j] = __cosf(pv[j] + rx[j]);
    Frag o;
    float suf = t[1];
    #pragma unroll
    for (int j = 2; j < 8; ++j) suf *= t[j];
    o.h[0] = __float2bfloat16(suf);
    float pr = t[0];
    #pragma unroll
    for (int j = 1; j < 8; ++j) { pr *= t[j]; o.h[j] = __float2bfloat16(pr); }
    *(s16x8*)(V + (size_t)(m0 + row) * EN + n0 + g * 8) = o.v;
}

// Kernel 2: out = V @ Wc^T + bc.  V, wcb bf16 (async frag-ordered staging).
__global__ __launch_bounds__(512, 4) void gemm2_kernel(
        const __hip_bfloat16* __restrict__ V,
        const __hip_bfloat16* __restrict__ wcb,
        const float* __restrict__ bc, float* __restrict__ out)
{
    __shared__ __align__(16) __hip_bfloat16 lds[16384];   // 32 KB

    const int tid  = threadIdx.x;
    const int wave = tid >> 6, lane = tid & 63;
    const int l15 = lane & 15, lq = lane >> 4;
    const int m0 = blockIdx.x * 64, n0 = blockIdx.y * 64;
    const int wmt = wave >> 1, wnt = wave & 1;

    const __hip_bfloat16* gsrc[2];
    int ldst[2];
    #pragma unroll
    for (int i = 0; i < 2; ++i) {
        const int t = wave * 2 + i;
        const __hip_bfloat16* base;
        int row, lofs;
        if (t < 8) { base = V;   row = m0 + (t >> 1) * 16 + l15; lofs = t * 512; }
        else       { const int u = t - 8; base = wcb; row = n0 + (u >> 1) * 16 + l15; lofs = 4096 + u * 512; }
        gsrc[i] = base + (size_t)row * EN + (t & 1) * 32 + lq * 8;
        ldst[i] = lofs;          // wave-uniform; HW adds lane*16B
    }

    f32x4 acc[2] = {};

    #pragma unroll
    for (int i = 0; i < 2; ++i) gll16(gsrc[i], &lds[ldst[i]]);
    __syncthreads();

    int p = 0;
    for (int it = 1; it <= 16; ++it) {
        if (it < 16) {
            const int q = p ^ 1;
            #pragma unroll
            for (int i = 0; i < 2; ++i) gll16(gsrc[i] + it * 64, &lds[q * 8192 + ldst[i]]);
        }
        const __hip_bfloat16* Ab = &lds[p * 8192];
        const __hip_bfloat16* Bb = Ab + 4096;
        #pragma unroll
        for (int kt = 0; kt < 2; ++kt) {
            s16x8 a = *(const s16x8*)&Ab[(wmt * 2 + kt) * 512 + lane * 8];
            #pragma unroll
            for (int j = 0; j < 2; ++j) {
                s16x8 b = *(const s16x8*)&Bb[((wnt * 2 + j) * 2 + kt) * 512 + lane * 8];
                acc[j] = __builtin_amdgcn_mfma_f32_16x16x32_bf16(a, b, acc[j], 0, 0, 0);
            }
        }
        __syncthreads();   // drains vmcnt: next buffer staged; reads of p done
        p ^= 1;
    }

    #pragma unroll
    for (int j = 0; j < 2; ++j) {
        const int col = n0 + wnt * 32 + j * 16 + l15;
        const float bv = bc[col];
        #pragma unroll
        for (int r = 0; r < 4; ++r) {
            const int row = m0 + wmt * 16 + lq * 4 + r;
            out[(size_t)row * EN + col] = acc[j][r] + bv;
        }
    }
}

extern "C" void kernel_launch(void* const* d_in, const int* in_sizes, int n_in,
                              void* d_out, int out_size, void* d_ws, size_t ws_size,
                              hipStream_t stream)
{
    // inputs: x, wq, wk, wv, wc, bc, rx_params (wq/wk dead: S==1)
    const float* x  = (const float*)d_in[0];
    const float* wv = (const float*)d_in[3];
    const float* wc = (const float*)d_in[4];
    const float* bc = (const float*)d_in[5];
    const float* rx = (const float*)d_in[6];
    float* out = (float*)d_out;

    const size_t WE = (size_t)EN * EN;
    // ws (6 MB): [wcb 2MB | V 4MB]
    __hip_bfloat16* wcb = (__hip_bfloat16*)d_ws;
    __hip_bfloat16* V   = wcb + WE;

    dim3 grid(BB / 64, EN / 64);   // 32 x 16 = 512 blocks
    gemm1q_kernel<<<grid, 512, 0, stream>>>(x, wv, wc, rx, wcb, V);
    gemm2_kernel<<<grid, 512, 0, stream>>>(V, wcb, bc, out);
}